// Round 1
// baseline (212.178 us; speedup 1.0000x reference)
//
#include <hip/hip_runtime.h>
#include <hip/hip_bf16.h>
#include <math.h>

// AFM forward, algebraically reduced.
//
// Key observation: the reference applies softmax over an axis of SIZE 1
// (s has shape [B,325,1], softmax axis=-1), which yields exactly 1.0.
// Therefore pooled[b,:] = sum_p pair[b,p,:], and the attention MLP
// (attn_w_*, attn_h_*) has zero effect on the output.
//
//   x[b]   = sum_{i<j} dot(emb_i, emb_j)
//          = 0.5 * sum_e [ (sum_i emb[b,i,e])^2 - sum_i emb[b,i,e]^2 ]   (FM identity)
//   out[b] = sigmoid(x[b] * out_kernel[0,0] + out_bias[0])
//
// Layout: 16 lanes per batch row, lane = embedding dim. Each field's
// embedding row is 16 contiguous floats (64 B) -> one coalesced segment
// per 16-lane group. 26 independent gathers per lane, then a 4-step
// shuffle reduction within the 16-lane group.

#define B_ROWS 4096
#define N_SPARSE 26
#define VOCAB 100000
#define EMB 16

__global__ __launch_bounds__(256) void AFM_6700148981883_kernel(
    const int* __restrict__ ids,       // [B, 26]
    const float* __restrict__ tables,  // [26, VOCAB, 16]
    const float* __restrict__ out_k,   // [1,1]
    const float* __restrict__ out_b,   // [1]
    float* __restrict__ out)           // [B]
{
    int tid = blockIdx.x * blockDim.x + threadIdx.x;
    int row = tid >> 4;        // batch index
    int e   = tid & 15;        // embedding dim (lane within group of 16)
    if (row >= B_ROWS) return;

    const int* rid = ids + row * N_SPARSE;

    float s = 0.0f, sq = 0.0f;
#pragma unroll
    for (int i = 0; i < N_SPARSE; ++i) {
        int id = rid[i];
        float v = tables[((size_t)i * VOCAB + (size_t)id) * EMB + e];
        s  += v;
        sq += v * v;
    }

    // Per-dim pairwise sum via FM identity.
    float x = 0.5f * (s * s - sq);

    // Reduce the 16 per-dim partials within the 16-lane group.
    x += __shfl_xor(x, 8, 16);
    x += __shfl_xor(x, 4, 16);
    x += __shfl_xor(x, 2, 16);
    x += __shfl_xor(x, 1, 16);

    if (e == 0) {
        float z = x * out_k[0] + out_b[0];
        out[row] = 1.0f / (1.0f + expf(-z));
    }
}

extern "C" void kernel_launch(void* const* d_in, const int* in_sizes, int n_in,
                              void* d_out, int out_size, void* d_ws, size_t ws_size,
                              hipStream_t stream) {
    // Inputs (setup_inputs() order):
    //  0: dense_x        [4096,13]  f32  (unused — sliced off in reference)
    //  1: sparse_ids     [4096,26]  i32
    //  2: embed_tables   [26,100000,16] f32
    //  3: attn_w_kernel  (dead code — softmax over size-1 axis)
    //  4: attn_w_bias    (dead)
    //  5: attn_h_kernel  (dead)
    //  6: attn_h_bias    (dead)
    //  7: out_kernel     [1,1] f32
    //  8: out_bias       [1]   f32
    const int*   ids    = (const int*)  d_in[1];
    const float* tables = (const float*)d_in[2];
    const float* out_k  = (const float*)d_in[7];
    const float* out_b  = (const float*)d_in[8];
    float* out = (float*)d_out;

    const int threads = B_ROWS * 16;   // 16 lanes per row
    const int block = 256;
    AFM_6700148981883_kernel<<<(threads + block - 1) / block, block, 0, stream>>>(
        ids, tables, out_k, out_b, out);
}

// Round 2
// 211.401 us; speedup vs baseline: 1.0037x; 1.0037x over previous
//
#include <hip/hip_runtime.h>
#include <hip/hip_bf16.h>
#include <math.h>

// AFM forward, algebraically reduced (see R0):
//   softmax over size-1 axis == 1.0  =>  attention MLP is dead code.
//   x[b]   = sum_{i<j} dot(emb_i, emb_j)
//          = 0.5 * sum_e [ (sum_i v_ie)^2 - sum_i v_ie^2 ]       (FM identity)
//   out[b] = sigmoid(x[b] * out_kernel + out_bias)
//
// R1 change: latency-hiding. R0 ran 256 blocks (1 block/CU, 4 waves/CU) with
// 26 gathers/thread. Now: 64 threads per batch row (16 dims x 4 field-splits),
// 1024 blocks -> 4 blocks/CU, 16 waves/CU, ~7 gathers/thread. Field splits
// are recombined BEFORE squaring (cross term) via shfl_xor(16/32); ids are
// loaded once per wave (one per lane) and broadcast with __shfl.

#define B_ROWS 4096
#define N_SPARSE 26
#define VOCAB 100000
#define EMB 16

// Field ranges per part: {0..6}, {7..13}, {14..19}, {20..25}
__device__ __constant__ int kPartStart[5] = {0, 7, 14, 20, 26};

__global__ __launch_bounds__(256) void AFM_6700148981883_kernel(
    const int* __restrict__ ids,       // [B, 26]
    const float* __restrict__ tables,  // [26, VOCAB, 16]
    const float* __restrict__ out_k,   // [1,1]
    const float* __restrict__ out_b,   // [1]
    float* __restrict__ out)           // [B]
{
    int tid  = blockIdx.x * blockDim.x + threadIdx.x;
    int row  = tid >> 6;          // batch index: one full wave per row
    int t    = tid & 63;          // lane within the row's wave
    int e    = t & 15;            // embedding dim
    int part = t >> 4;            // field split 0..3

    // One id per lane, broadcast later. Lanes 0..25 load ids[row][lane].
    const int* rid = ids + row * N_SPARSE;
    int myid = (t < N_SPARSE) ? rid[t] : 0;

    int f0 = kPartStart[part];
    int f1 = kPartStart[part + 1];

    float s = 0.0f, sq = 0.0f;
#pragma unroll 7
    for (int f = f0; f < f1; ++f) {
        int id = __shfl(myid, f, 64);  // broadcast ids[row][f] from lane f
        float v = tables[((size_t)f * VOCAB + (size_t)id) * EMB + e];
        s  += v;
        sq += v * v;
    }

    // Combine the 4 field-splits' sums per dim BEFORE squaring (cross terms).
    s += __shfl_xor(s, 16, 64);
    s += __shfl_xor(s, 32, 64);
    // Each of the 4 parts now holds s_tot(e). Each contributes 1/4 of the
    // 0.5*s_tot^2 term and its own -0.5*sq.
    float y = 0.125f * s * s - 0.5f * sq;

    // Full 64-lane reduction of y (sums over dims and parts).
    y += __shfl_xor(y, 1, 64);
    y += __shfl_xor(y, 2, 64);
    y += __shfl_xor(y, 4, 64);
    y += __shfl_xor(y, 8, 64);
    y += __shfl_xor(y, 16, 64);
    y += __shfl_xor(y, 32, 64);

    if (t == 0) {
        float z = y * out_k[0] + out_b[0];
        out[row] = 1.0f / (1.0f + expf(-z));
    }
}

extern "C" void kernel_launch(void* const* d_in, const int* in_sizes, int n_in,
                              void* d_out, int out_size, void* d_ws, size_t ws_size,
                              hipStream_t stream) {
    // Inputs (setup_inputs() order):
    //  0: dense_x (unused)  1: sparse_ids [4096,26] i32
    //  2: embed_tables [26,100000,16] f32
    //  3..6: attention params (dead code: softmax over size-1 axis)
    //  7: out_kernel [1,1] f32   8: out_bias [1] f32
    const int*   ids    = (const int*)  d_in[1];
    const float* tables = (const float*)d_in[2];
    const float* out_k  = (const float*)d_in[7];
    const float* out_b  = (const float*)d_in[8];
    float* out = (float*)d_out;

    const int threads = B_ROWS * 64;   // one wave per row
    const int block = 256;
    AFM_6700148981883_kernel<<<(threads + block - 1) / block, block, 0, stream>>>(
        ids, tables, out_k, out_b, out);
}